// Round 1
// baseline (131.186 us; speedup 1.0000x reference)
//
#include <hip/hip_runtime.h>
#include <hip/hip_bf16.h>
#include <stdint.h>

// Problem constants
#define BATCH 4096
#define NT    8192          // 2*BATCH
#define FD    256           // feature dim
#define TILE  128           // block tile (TILE x TILE of the pair matrix)
#define BK    64            // K chunk per staging iteration
#define NUMK  5

typedef __attribute__((ext_vector_type(8))) short bf16x8;  // 8 bf16 = 4 VGPRs
typedef __attribute__((ext_vector_type(4))) float f32x4;

// ---- workspace layout (bytes) ----
// [0, 4 MiB)            bf16 feats [8192][256]
// WS_SQ    = 4 MiB      sq[8192] f32
// WS_COL   = +32 KiB    colsum[256] f32   (memset 0)
// WS_SUMSQ = +1024      sumsq f32         (memset 0)
// WS_GAMMA = +4         gamma0 f32
static const size_t WS_FB    = 0;
static const size_t WS_SQ    = (size_t)NT * FD * 2;        // 4194304
static const size_t WS_COL   = WS_SQ + (size_t)NT * 4;     // +32768
static const size_t WS_SUMSQ = WS_COL + 256 * 4;           // +1024
static const size_t WS_GAMMA = WS_SUMSQ + 4;

__device__ __forceinline__ unsigned short f2bf_rne(float x) {
    unsigned u = __float_as_uint(x);
    unsigned r = (u + 0x7fffu + ((u >> 16) & 1u)) >> 16;
    return (unsigned short)r;
}

__device__ __forceinline__ void async_copy16(void* lds, const void* g) {
    __builtin_amdgcn_global_load_lds(
        (__attribute__((address_space(1))) void*)(void*)(const_cast<void*>(g)),
        (__attribute__((address_space(3))) void*)lds, 16, 0, 0);
}

// ---------------- kernel 1: convert + row norms + column sums ----------------
__global__ void mmd_prep(const float* __restrict__ s_feat,
                         const float* __restrict__ t_feat,
                         unsigned short* __restrict__ fb,
                         float* __restrict__ sq,
                         float* __restrict__ colsum,
                         float* __restrict__ sumsq) {
    __shared__ float cp[4][FD];
    const int w    = threadIdx.x >> 6;
    const int lane = threadIdx.x & 63;
    float c0 = 0.f, c1 = 0.f, c2 = 0.f, c3 = 0.f;
    float wtot = 0.f;
    for (int t = 0; t < 8; ++t) {
        int row = blockIdx.x * 32 + w * 8 + t;
        const float* src = (row < BATCH) ? (s_feat + (size_t)row * FD)
                                         : (t_feat + (size_t)(row - BATCH) * FD);
        float4 v = ((const float4*)src)[lane];
        unsigned int u01 = (unsigned)f2bf_rne(v.x) | ((unsigned)f2bf_rne(v.y) << 16);
        unsigned int u23 = (unsigned)f2bf_rne(v.z) | ((unsigned)f2bf_rne(v.w) << 16);
        ((uint2*)(fb + (size_t)row * FD))[lane] = make_uint2(u01, u23);
        float ss = v.x * v.x + v.y * v.y + v.z * v.z + v.w * v.w;
        for (int off = 32; off; off >>= 1) ss += __shfl_down(ss, off);
        if (lane == 0) { sq[row] = ss; wtot += ss; }
        c0 += v.x; c1 += v.y; c2 += v.z; c3 += v.w;
    }
    if (lane == 0) atomicAdd(sumsq, wtot);
    cp[w][4 * lane + 0] = c0;
    cp[w][4 * lane + 1] = c1;
    cp[w][4 * lane + 2] = c2;
    cp[w][4 * lane + 3] = c3;
    __syncthreads();
    int t = threadIdx.x;
    float s = cp[0][t] + cp[1][t] + cp[2][t] + cp[3][t];
    atomicAdd(&colsum[t], s);
}

// ---------------- kernel 2: bandwidth -> gamma0 ----------------
__global__ void mmd_gamma(const float* __restrict__ colsum,
                          const float* __restrict__ sumsq,
                          float* __restrict__ gamma) {
    __shared__ float red[4];
    int t = threadIdx.x;
    float c = colsum[t];
    float v = c * c;
    int lane = t & 63, w = t >> 6;
    for (int off = 32; off; off >>= 1) v += __shfl_down(v, off);
    if (lane == 0) red[w] = v;
    __syncthreads();
    if (t == 0) {
        float s2 = red[0] + red[1] + red[2] + red[3];
        // sum(distances) = 2*n*sum(sq) - 2*||colsum||^2  (clamp effect negligible)
        float sumd = 2.0f * (float)NT * sumsq[0] - 2.0f * s2;
        float n2n  = (float)((long long)NT * NT - NT);   // n^2 - n
        float bw   = n2n / sumd;
        gamma[0]   = 0.25f * bw;   // / 2^(NUM_KERNELS//2)
    }
}

// ---------------- kernel 3: fused GEMM + gaussian-kernel + reduce ----------------
__global__ __launch_bounds__(256) void mmd_main(
    const unsigned short* __restrict__ fb,
    const float* __restrict__ sq,
    const float* __restrict__ gamma,
    float* __restrict__ out) {
    const int bj = blockIdx.x, bi = blockIdx.y;
    if (bj < bi) return;   // upper triangle only (whole-block uniform)

    __shared__ __align__(16) unsigned short a_t[TILE * BK];
    __shared__ __align__(16) unsigned short b_t[TILE * BK];
    __shared__ float sqa[TILE], sqb[TILE];
    __shared__ float red[4];

    const int tid  = threadIdx.x;
    const int w    = tid >> 6, lane = tid & 63;
    const int wm   = w & 1, wn = w >> 1;         // 2x2 waves over 128x128
    const int quad = lane >> 4, m16 = lane & 15;
    const int lrow   = lane >> 3;                // 0..7 (row within 8-row group)
    const int lchunk = lane & 7;                 // physical 16B-chunk slot

    if (tid < TILE) sqa[tid] = sq[bi * TILE + tid];
    else            sqb[tid - TILE] = sq[bj * TILE + (tid - TILE)];

    const f32x4 fzero = {0.f, 0.f, 0.f, 0.f};
    f32x4 acc[4][4];
#pragma unroll
    for (int a = 0; a < 4; ++a)
#pragma unroll
        for (int b = 0; b < 4; ++b) acc[a][b] = fzero;

    const size_t rowA0 = (size_t)bi * TILE;
    const size_t rowB0 = (size_t)bj * TILE;
    const int gc = lchunk ^ lrow;   // XOR-swizzle: slot p holds global chunk p^(row&7)

    for (int k0 = 0; k0 < FD; k0 += BK) {
        __syncthreads();   // protect LDS reuse from previous iteration's reads
#pragma unroll
        for (int q = 0; q < 4; ++q) {
            int r = q * 32 + w * 8 + lrow;   // (r & 7) == lrow
            const unsigned short* ga = fb + (rowA0 + r) * FD + k0 + gc * 8;
            async_copy16(&a_t[(q * 32 + w * 8) * BK], ga);
        }
#pragma unroll
        for (int q = 0; q < 4; ++q) {
            int r = q * 32 + w * 8 + lrow;
            const unsigned short* gb = fb + (rowB0 + r) * FD + k0 + gc * 8;
            async_copy16(&b_t[(q * 32 + w * 8) * BK], gb);
        }
        __syncthreads();   // drains vmcnt (global_load_lds) per compiler barrier semantics

#pragma unroll
        for (int kk = 0; kk < BK; kk += 32) {
            bf16x8 af[4], bf[4];
            const int cl = (kk >> 3) + quad;   // logical 16B chunk 0..7
#pragma unroll
            for (int tm = 0; tm < 4; ++tm) {
                int row = wm * 64 + tm * 16 + m16;
                int p = cl ^ (row & 7);
                af[tm] = *(const bf16x8*)&a_t[row * BK + p * 8];
            }
#pragma unroll
            for (int tn = 0; tn < 4; ++tn) {
                int row = wn * 64 + tn * 16 + m16;
                int p = cl ^ (row & 7);
                bf[tn] = *(const bf16x8*)&b_t[row * BK + p * 8];
            }
#pragma unroll
            for (int tm = 0; tm < 4; ++tm)
#pragma unroll
                for (int tn = 0; tn < 4; ++tn)
                    acc[tm][tn] = __builtin_amdgcn_mfma_f32_16x16x32_bf16(
                        af[tm], bf[tn], acc[tm][tn], 0, 0, 0);
        }
    }

    // ---- epilogue: d = sq_i + sq_j - 2 dot, clamp, e + e^2 + e^4 + e^8 + e^16 ----
    const float g0 = gamma[0];
    float lsum = 0.f;
#pragma unroll
    for (int tm = 0; tm < 4; ++tm) {
        const int i0 = wm * 64 + tm * 16 + quad * 4;
        float sqi0 = sqa[i0 + 0], sqi1 = sqa[i0 + 1], sqi2 = sqa[i0 + 2], sqi3 = sqa[i0 + 3];
#pragma unroll
        for (int tn = 0; tn < 4; ++tn) {
            const int j = wn * 64 + tn * 16 + m16;
            const float sqj = sqb[j];
            float sqi[4] = {sqi0, sqi1, sqi2, sqi3};
#pragma unroll
            for (int r = 0; r < 4; ++r) {
                float d = fmaf(-2.f, acc[tm][tn][r], sqi[r] + sqj);
                d = fmaxf(d, 0.f);
                float e1 = __expf(-d * g0);
                float e2 = e1 * e1, e4 = e2 * e2, e8 = e4 * e4, e16 = e8 * e8;
                lsum += e1 + e2 + e4 + e8 + e16;
            }
        }
    }
    for (int off = 32; off; off >>= 1) lsum += __shfl_down(lsum, off);
    if (lane == 0) red[w] = lsum;
    __syncthreads();
    if (tid == 0) {
        float wgt;
        if (bi == bj) wgt = 1.f;                                  // diagonal tile, once
        else wgt = ((bi < 32) == (bj < 32)) ? 2.f : -2.f;         // mirrored tile folded in
        // disc = sum / (NUMK * BATCH^2); 1/4096^2 = 2^-24 exact
        float scale = wgt * (1.f / NUMK) * (1.f / 16777216.f);
        atomicAdd(out, (red[0] + red[1] + red[2] + red[3]) * scale);
    }
}

extern "C" void kernel_launch(void* const* d_in, const int* in_sizes, int n_in,
                              void* d_out, int out_size, void* d_ws, size_t ws_size,
                              hipStream_t stream) {
    const float* s_feat = (const float*)d_in[0];
    const float* t_feat = (const float*)d_in[1];
    char* ws = (char*)d_ws;
    unsigned short* fb = (unsigned short*)(ws + WS_FB);
    float* sq     = (float*)(ws + WS_SQ);
    float* colsum = (float*)(ws + WS_COL);
    float* sumsq  = (float*)(ws + WS_SUMSQ);
    float* gamma  = (float*)(ws + WS_GAMMA);
    float* out    = (float*)d_out;

    hipMemsetAsync(ws + WS_COL, 0, 256 * 4 + 4, stream);  // colsum + sumsq
    hipMemsetAsync(d_out, 0, sizeof(float), stream);

    mmd_prep<<<NT / 32, 256, 0, stream>>>(s_feat, t_feat, fb, sq, colsum, sumsq);
    mmd_gamma<<<1, 256, 0, stream>>>(colsum, sumsq, gamma);
    mmd_main<<<dim3(64, 64), 256, 0, stream>>>(fb, sq, gamma, out);
}